// Round 12
// baseline (740.702 us; speedup 1.0000x reference)
//
#include <hip/hip_runtime.h>
#include <hip/hip_bf16.h>
#include <hip/hip_cooperative_groups.h>

namespace cg = cooperative_groups;

typedef unsigned short u16;
typedef u16   u16x8 __attribute__((ext_vector_type(8)));
typedef short s16x8 __attribute__((ext_vector_type(8)));
typedef float f32x4 __attribute__((ext_vector_type(4)));

__device__ __forceinline__ float bf2f(u16 u) {
    union { unsigned int i; float f; } v; v.i = ((unsigned int)u) << 16; return v.f;
}
__device__ __forceinline__ u16 f2bf(float f) {
    unsigned int x = __float_as_uint(f);
    return (u16)((x + 0x7fffu + ((x >> 16) & 1u)) >> 16);   // RNE
}
__device__ __forceinline__ float ldv(const void* p, size_t i, int f32) {
    return f32 ? ((const float*)p)[i] : bf2f(((const u16*)p)[i]);
}

struct P21 { const void* p[21]; };
// p[]: 0 cw1,1 cb1,2 cw2,3 cb2,4 cw3,5 cb3,6 vw,7 vb,8 lvl,
//      9 sw0,10 sb0,11 aw0,12 ab0,13 ow0,14 ob0, 15 sw1,16 sb1,17 aw1,18 ab1,19 ow1,20 ob1

struct MegaArgs {
    P21 a;
    const void *f00, *f01, *f10, *f11;
    u16 *AW1, *AW2, *AW3, *AVW, *APJ0, *APJ1, *AOP0, *AOP1, *BPJ0, *BPJ1, *SB;
    u16 *CATT, *X0, *VAL, *CH1, *CH2, *QT0, *QT1, *S;
    float* PA;
    void* OUT;
};

// ===========================================================================
// GEMM core, BK=64, tile 64 x BN (BN = 64 or 32). 4 waves. (f32o by value)
// OUTM=0: C[m][nbase+n] (ldc). OUTM=1: C^T[nbase+n][m] bounce. OUTM=2: NCHW out.
// ===========================================================================
template<int ACT, int OUTM, int OUT_BF16, int BN>
__device__ __forceinline__ void gemm_body(
    u16* __restrict__ smem, int bid,
    const u16* __restrict__ A, const u16* __restrict__ Bt,
    const u16* __restrict__ bias, void* __restrict__ Cv,
    int M, int K, int ldc, int nbase, int f32o)
{
    constexpr int NF = BN >> 4;
    u16 (*As)[72] = (u16(*)[72])smem;
    u16 (*Bs)[72] = (u16(*)[72])(smem + 4608);

    const int t    = threadIdx.x;
    const int wv   = t >> 6, lane = t & 63;
    const int fr   = lane & 15, fg = lane >> 4;
    const int tiles_m = M >> 6;
    const int bm = bid % tiles_m, bn = bid / tiles_m;
    const int m0 = bm << 6, n0 = bn * BN;

    f32x4 acc[NF] = {};
    const int srow = t >> 2;
    const int scol = (t & 3) << 4;
    const int brow = (BN == 64) ? srow : (t >> 3);
    const int bcol = (BN == 64) ? scol : ((t & 7) << 3);
    const u16* Ap = A  + (size_t)(m0 + srow) * K + scol;
    const u16* Bp = Bt + (size_t)(n0 + brow) * K + bcol;

    const int ns = K >> 6;
    uint4 av0 = *(const uint4*)Ap, av1 = *(const uint4*)(Ap + 8);
    uint4 bv0 = *(const uint4*)Bp, bv1 = {0,0,0,0};
    if constexpr (BN == 64) bv1 = *(const uint4*)(Bp + 8);
    for (int s = 0; s < ns; ++s) {
        __syncthreads();
        *(uint4*)&As[srow][scol]     = av0;  *(uint4*)&As[srow][scol + 8] = av1;
        *(uint4*)&Bs[brow][bcol]     = bv0;
        if constexpr (BN == 64) *(uint4*)&Bs[brow][bcol + 8] = bv1;
        __syncthreads();
        if (s + 1 < ns) {
            const u16* An = Ap + ((s + 1) << 6);
            const u16* Bn = Bp + ((s + 1) << 6);
            av0 = *(const uint4*)An;  av1 = *(const uint4*)(An + 8);
            bv0 = *(const uint4*)Bn;
            if constexpr (BN == 64) bv1 = *(const uint4*)(Bn + 8);
        }
        union U { uint4 q; s16x8 v; };
        #pragma unroll
        for (int kk = 0; kk < 2; ++kk) {
            U af; af.q = *(const uint4*)&As[(wv << 4) + fr][(kk << 5) + (fg << 3)];
            U bf[NF];
            #pragma unroll
            for (int j = 0; j < NF; ++j)
                bf[j].q = *(const uint4*)&Bs[(j << 4) + fr][(kk << 5) + (fg << 3)];
            #pragma unroll
            for (int j = 0; j < NF; ++j)
                acc[j] = __builtin_amdgcn_mfma_f32_16x16x32_bf16(af.v, bf[j].v, acc[j], 0, 0, 0);
        }
    }

    float vv[NF][4];
    #pragma unroll
    for (int r = 0; r < 4; ++r) {
        float bvv = bf2f(bias[m0 + (wv << 4) + (fg << 2) + r]);
        #pragma unroll
        for (int j = 0; j < NF; ++j) {
            float v = acc[j][r] + bvv;
            if (ACT) v = (v >= 0.f) ? v : 0.1f * v;
            vv[j][r] = v;
        }
    }

    if constexpr (OUTM == 0) {
        #pragma unroll
        for (int j = 0; j < NF; ++j)
            #pragma unroll
            for (int r = 0; r < 4; ++r) {
                size_t idx = (size_t)(m0 + (wv << 4) + (fg << 2) + r) * ldc
                           + (nbase + n0 + (j << 4) + fr);
                if (OUT_BF16) ((u16*)Cv)[idx] = f2bf(vv[j][r]);
                else          ((float*)Cv)[idx] = vv[j][r];
            }
    } else if constexpr (OUTM == 1) {
        __syncthreads();
        u16* bb = smem;                                 // [BN n][72 m]
        #pragma unroll
        for (int j = 0; j < NF; ++j)
            #pragma unroll
            for (int r = 0; r < 4; ++r)
                bb[((j << 4) + fr) * 72 + (wv << 4) + (fg << 2) + r] = f2bf(vv[j][r]);
        __syncthreads();
        if constexpr (BN == 64) {
            int row = t >> 2, seg = (t & 3) << 4;
            const uint4* src = (const uint4*)&bb[row * 72 + seg];
            uint4* dst = (uint4*)((u16*)Cv + (size_t)(nbase + n0 + row) * M + m0 + seg);
            dst[0] = src[0];
            dst[1] = src[1];
        } else {
            int row = t >> 3, seg = (t & 7) << 3;
            const uint4* src = (const uint4*)&bb[row * 72 + seg];
            uint4* dst = (uint4*)((u16*)Cv + (size_t)(nbase + n0 + row) * M + m0 + seg);
            dst[0] = src[0];
        }
    } else {
        __syncthreads();
        constexpr int LDB = BN + 8;
        u16* bb = smem;                                 // [64 m][LDB n]
        #pragma unroll
        for (int j = 0; j < NF; ++j)
            #pragma unroll
            for (int r = 0; r < 4; ++r)
                bb[((wv << 4) + (fg << 2) + r) * LDB + (j << 4) + fr] = f2bf(vv[j][r]);
        __syncthreads();
        constexpr int EPT = BN / 4;
        int mrow = t >> 2, seg = (t & 3) * EPT;
        int b = n0 / 1536, hw0 = (n0 % 1536) + seg;
        size_t base = (size_t)(b * 128 + m0 + mrow) * 1536 + hw0;
        if (!f32o) {
            #pragma unroll
            for (int q = 0; q < EPT / 8; ++q)
                *(uint4*)((u16*)Cv + base + q * 8) = *(const uint4*)&bb[mrow * LDB + seg + q * 8];
        } else {
            float* dst = (float*)Cv + base;
            #pragma unroll
            for (int j = 0; j < EPT; ++j) dst[j] = bf2f(bb[mrow * LDB + seg + j]);
        }
    }
}

// ===========================================================================
// Implicit-GEMM 3x3 conv (pad 1), BK=64, tile 64 x BN. POS=1 fuses pos-enc.
// ===========================================================================
template<int CIN, int POS, int BN>
__device__ __forceinline__ void conv_body(
    u16* __restrict__ smem, int bid,
    const u16* __restrict__ A, const u16* __restrict__ X,
    const u16* __restrict__ bias, u16* __restrict__ Cv, int M)
{
    constexpr int NF = BN >> 4;
    u16 (*As)[72] = (u16(*)[72])smem;
    u16 (*Bs)[72] = (u16(*)[72])(smem + 4608);

    constexpr int NK2 = CIN / 64;
    constexpr int TOT = 9 * NK2;

    const int t    = threadIdx.x;
    const int wv   = t >> 6, lane = t & 63;
    const int fr   = lane & 15, fg = lane >> 4;
    const int tiles_m = M >> 6;
    const int bm = bid % tiles_m, bn = bid / tiles_m;
    const int m0 = bm << 6, n0 = bn * BN;

    const int srow = t >> 2;
    const int scol = (t & 3) << 4;
    const int brow = (BN == 64) ? srow : (t >> 3);
    const int bcol = (BN == 64) ? scol : ((t & 7) << 3);
    const int n  = n0 + brow;
    const int hw = n % 1536;
    const int hp = hw / 48, wp = hw % 48;
    const u16* Ar = A + (size_t)(m0 + srow) * (9 * CIN) + scol;

    f32x4 acc[NF] = {};

    auto ld = [&](int s, uint4& a0, uint4& a1, uint4& b0, uint4& b1) {
        int tap = s / NK2, k0 = (s % NK2) << 6;
        int dy = tap / 3 - 1, dx = tap % 3 - 1;
        bool vr = ((unsigned)(hp + dy) < 32u) && ((unsigned)(wp + dx) < 48u);
        const u16* Ap = Ar + tap * CIN + k0;
        a0 = *(const uint4*)Ap;  a1 = *(const uint4*)(Ap + 8);
        if (vr) {
            const u16* Bp = X + (size_t)(n + dy * 48 + dx) * CIN + bcol + k0;
            b0 = *(const uint4*)Bp;
            if constexpr (BN == 64) b1 = *(const uint4*)(Bp + 8);
        } else {
            b0 = uint4{0,0,0,0};  b1 = uint4{0,0,0,0};
        }
    };

    uint4 av0, av1, bv0, bv1;
    ld(0, av0, av1, bv0, bv1);
    for (int s = 0; s < TOT; ++s) {
        __syncthreads();
        *(uint4*)&As[srow][scol]     = av0;  *(uint4*)&As[srow][scol + 8] = av1;
        *(uint4*)&Bs[brow][bcol]     = bv0;
        if constexpr (BN == 64) *(uint4*)&Bs[brow][bcol + 8] = bv1;
        __syncthreads();
        if (s + 1 < TOT) ld(s + 1, av0, av1, bv0, bv1);
        union U { uint4 q; s16x8 v; };
        #pragma unroll
        for (int kk = 0; kk < 2; ++kk) {
            U af; af.q = *(const uint4*)&As[(wv << 4) + fr][(kk << 5) + (fg << 3)];
            U bf[NF];
            #pragma unroll
            for (int j = 0; j < NF; ++j)
                bf[j].q = *(const uint4*)&Bs[(j << 4) + fr][(kk << 5) + (fg << 3)];
            #pragma unroll
            for (int j = 0; j < NF; ++j)
                acc[j] = __builtin_amdgcn_mfma_f32_16x16x32_bf16(af.v, bf[j].v, acc[j], 0, 0, 0);
        }
    }

    float vv[NF][4];
    #pragma unroll
    for (int r = 0; r < 4; ++r) {
        float bvv = bf2f(bias[m0 + (wv << 4) + (fg << 2) + r]);
        #pragma unroll
        for (int j = 0; j < NF; ++j) {
            float v = acc[j][r] + bvv;
            vv[j][r] = (v >= 0.f) ? v : 0.1f * v;
        }
    }

    if (POS) {
        const float TWO_PI = 6.283185307179586f;
        #pragma unroll
        for (int j = 0; j < NF; ++j) {
            int ntok = n0 + (j << 4) + fr;
            int hw2 = ntok % 1536;
            int hp2 = hw2 / 48, wp2 = hw2 % 48;
            float yv = (float)(hp2 + 1) * (TWO_PI / (32.f + 1e-6f));
            float xv = (float)(wp2 + 1) * (TWO_PI / (48.f + 1e-6f));
            #pragma unroll
            for (int r = 0; r < 4; ++r) {
                int d = m0 + (wv << 4) + (fg << 2) + r;
                int mm = (d & 63) >> 1;
                float dim = exp2f((float)mm * (13.287712379549449f / 32.f));
                float val = ((d < 64) ? yv : xv) / dim;
                vv[j][r] += (d & 1) ? cosf(val) : sinf(val);
            }
        }
    }

    __syncthreads();
    u16* bb = smem;                                     // [BN n][72 m]
    #pragma unroll
    for (int j = 0; j < NF; ++j)
        #pragma unroll
        for (int r = 0; r < 4; ++r)
            bb[((j << 4) + fr) * 72 + (wv << 4) + (fg << 2) + r] = f2bf(vv[j][r]);
    __syncthreads();
    if constexpr (BN == 64) {
        int row = t >> 2, seg = (t & 3) << 4;
        const uint4* src = (const uint4*)&bb[row * 72 + seg];
        uint4* dst = (uint4*)(Cv + (size_t)(n0 + row) * M + m0 + seg);
        dst[0] = src[0];
        dst[1] = src[1];
    } else {
        int row = t >> 3, seg = (t & 7) << 3;
        const uint4* src = (const uint4*)&bb[row * 72 + seg];
        uint4* dst = (uint4*)(Cv + (size_t)(n0 + row) * M + m0 + seg);
        dst[0] = src[0];
    }
}

// ===========================================================================
// prep unit (shared by mega + standalone): u in [0,4774)
// ===========================================================================
__device__ void prep_unit(int u, int t, int f32, const MegaArgs& g, u16* Ts)
{
    const P21& a = g.a;
    if (u < 3718) {
        int gg = u * 256 + t;
        if (gg < 294912) { int m = gg / 1152, rem = gg % 1152, tap = rem >> 7, ci = rem & 127;
            g.AW1[gg] = f2bf(ldv(a.p[0], (size_t)m * 1152 + ci * 9 + tap, f32)); return; }
        gg -= 294912;
        if (gg < 294912) { int m = gg / 2304, rem = gg % 2304, tap = rem >> 8, ci = rem & 255;
            g.AW2[gg] = f2bf(ldv(a.p[2], (size_t)m * 2304 + ci * 9 + tap, f32)); return; }
        gg -= 294912;
        if (gg < 147456) { int m = gg / 1152, rem = gg % 1152, tap = rem >> 7, ci = rem & 127;
            g.AW3[gg] = f2bf(ldv(a.p[4], (size_t)m * 1152 + ci * 9 + tap, f32)); return; }
        gg -= 147456;
        if (gg < 32768) { g.AVW[gg] = f2bf(ldv(a.p[6], gg, f32)); return; }
        gg -= 32768;
        if (gg < 24576) { int o = gg >> 7, d = gg & 127;
            g.APJ0[gg] = f2bf(o < 128 ? ldv(a.p[9], d * 128 + o, f32)
                                      : ldv(a.p[11], d * 64 + (o - 128), f32)); return; }
        gg -= 24576;
        if (gg < 24576) { int o = gg >> 7, d = gg & 127;
            g.APJ1[gg] = f2bf(o < 128 ? ldv(a.p[15], d * 128 + o, f32)
                                      : ldv(a.p[17], d * 64 + (o - 128), f32)); return; }
        gg -= 24576;
        if (gg < 65536) { int o = gg >> 9, k = gg & 511; g.AOP0[gg] = f2bf(ldv(a.p[13], k * 128 + o, f32)); return; }
        gg -= 65536;
        if (gg < 65536) { int o = gg >> 9, k = gg & 511; g.AOP1[gg] = f2bf(ldv(a.p[19], k * 128 + o, f32)); return; }
        gg -= 65536;
        if (gg < 192) { g.BPJ0[gg] = f2bf(gg < 128 ? ldv(a.p[10], gg, f32) : ldv(a.p[12], gg - 128, f32)); return; }
        gg -= 192;
        if (gg < 192) { g.BPJ1[gg] = f2bf(gg < 128 ? ldv(a.p[16], gg, f32) : ldv(a.p[18], gg - 128, f32)); return; }
        gg -= 192;
        if (gg < 1152) {
            const int off[8] = {0, 256, 384, 512, 640, 896, 1024, 1152};
            const int src[7] = {1, 3, 5, 7, 8, 14, 20};
            int s = 0;
            #pragma unroll
            for (int i = 1; i < 7; ++i) s += (gg >= off[i]);
            g.SB[gg] = f2bf(ldv(a.p[src[s]], gg - off[s], f32));
        }
        return;
    }

    // feature transposes via LDS tile [128][66]
    const void* src; u16* dst;
    int b, hw0, HW, rowlen, coloff, lvl, addemb;
    if (u < 4678) {
        int gg = u - 3718;
        int half = gg & 1;  gg >>= 1;                 // 480 = 4b x 120 tiles
        b = gg / 120;  int tile = gg % 120;
        lvl = (tile >= 96) ? 1 : 0;
        int tl = lvl ? tile - 96 : tile;
        hw0 = tl << 6;
        HW = lvl ? 1536 : 6144;
        src = (half == 0) ? (lvl ? g.f01 : g.f00) : (lvl ? g.f11 : g.f10);
        dst = g.CATT + (size_t)(b * 7680 + lvl * 6144 + hw0) * 256;
        rowlen = 256; coloff = half << 7; addemb = 1;
    } else {
        int gg = u - 4678;                            // 96 = 4b x 24 tiles
        b = gg / 24;  hw0 = (gg % 24) << 6;
        HW = 1536; src = g.f01;
        dst = g.X0 + (size_t)(b * 1536 + hw0) * 128;
        rowlen = 128; coloff = 0; lvl = 1; addemb = 0;
    }

    {
        int c = t >> 1, hseg = (t & 1) << 5;
        size_t base = (size_t)(b * 128 + c) * HW + hw0 + hseg;
        u16* dstl = &Ts[c * 66 + hseg];
        if (!f32) {
            const u16* s8 = (const u16*)src + base;
            *(uint4*)(dstl)      = *(const uint4*)(s8);
            *(uint4*)(dstl + 8)  = *(const uint4*)(s8 + 8);
            *(uint4*)(dstl + 16) = *(const uint4*)(s8 + 16);
            *(uint4*)(dstl + 24) = *(const uint4*)(s8 + 24);
        } else {
            const float* sf = (const float*)src + base;
            #pragma unroll
            for (int q = 0; q < 32; ++q) dstl[q] = f2bf(sf[q]);
        }
    }
    __syncthreads();
    {
        int tok = t & 63, cseg = (t >> 6) << 5;
        u16 outv[32];
        #pragma unroll
        for (int j = 0; j < 32; ++j) {
            float x = bf2f(Ts[(cseg + j) * 66 + tok]);
            if (addemb) x += ldv(a.p[8], lvl * 128 + cseg + j, f32);
            outv[j] = f2bf(x);
        }
        u16* drow = dst + (size_t)tok * rowlen + coloff + cseg;
        #pragma unroll
        for (int q = 0; q < 4; ++q)
            *(uint4*)(drow + q * 8) = *(const uint4*)(&outv[q * 8]);
    }
}

// ===========================================================================
// msda unit: 2 tokens per 256-thr unit (R7 gather mapping, batched 16-deep)
// ===========================================================================
__device__ void msda_unit(int u, int t, const float* __restrict__ PA,
                          const u16* __restrict__ VAL, u16* __restrict__ S,
                          char* smem)
{
    int*   SMI = (int*)smem;                           // [4][128]
    float* SMW = (float*)(smem + 2048);                // [4][128]
    float* LG  = (float*)(smem + 4096);                // [128]
    float* EW  = (float*)(smem + 4608);                // [128]

    const int tok0 = ((u & 7) * 384 + (u >> 3)) << 1;  // XCD-chunked, 2 tok

    if (t < 128) {
        int tok = t >> 6, s = t & 63;
        int h = s >> 4, l = (s >> 3) & 1, p = s & 7;
        int orow = h * 32 + l * 16 + p * 2;
        int gtok = tok0 + tok;
        float offx = PA[(size_t)orow * 6144 + gtok];
        float offy = PA[(size_t)(orow + 1) * 6144 + gtok];
        LG[t]      = PA[(size_t)(128 + h * 16 + l * 8 + p) * 6144 + gtok];
        int b = gtok / 1536, hw = gtok % 1536;
        int hp = hw / 48, wp = hw % 48;
        float Wl = l ? 48.f : 96.f, Hl = l ? 32.f : 64.f;
        int iWl = l ? 48 : 96, iHl = l ? 32 : 64;
        int base = l ? 6144 : 0;
        float locx = (wp + 0.5f) / 48.f + offx / Wl;
        float locy = (hp + 0.5f) / 32.f + offy / Hl;
        float x = locx * Wl - 0.5f;
        float y = locy * Hl - 0.5f;
        float xf = floorf(x), yf = floorf(y);
        float fx = x - xf, fy = y - yf;
        int ix = (int)xf, iy = (int)yf;
        int vrow = b * 7680 + base;
        float w00 = (1.f - fx) * (1.f - fy), w01 = fx * (1.f - fy);
        float w10 = (1.f - fx) * fy,         w11 = fx * fy;
        bool vx0 = (unsigned)ix < (unsigned)iWl,       vx1 = (unsigned)(ix + 1) < (unsigned)iWl;
        bool vy0 = (unsigned)iy < (unsigned)iHl,       vy1 = (unsigned)(iy + 1) < (unsigned)iHl;
        SMI[0 * 128 + t] = (vx0 && vy0) ? vrow + iy * iWl + ix           : 0;
        SMI[1 * 128 + t] = (vx1 && vy0) ? vrow + iy * iWl + ix + 1       : 0;
        SMI[2 * 128 + t] = (vx0 && vy1) ? vrow + (iy + 1) * iWl + ix     : 0;
        SMI[3 * 128 + t] = (vx1 && vy1) ? vrow + (iy + 1) * iWl + ix + 1 : 0;
        SMW[0 * 128 + t] = (vx0 && vy0) ? w00 : 0.f;
        SMW[1 * 128 + t] = (vx1 && vy0) ? w01 : 0.f;
        SMW[2 * 128 + t] = (vx0 && vy1) ? w10 : 0.f;
        SMW[3 * 128 + t] = (vx1 && vy1) ? w11 : 0.f;
    }
    __syncthreads();
    if (t < 128) {
        int h0 = t & ~15;
        float mx = -1e30f;
        for (int i = 0; i < 16; ++i) mx = fmaxf(mx, LG[h0 + i]);
        EW[t] = expf(LG[t] - mx);
    }
    __syncthreads();
    if (t < 128) {
        int h0 = t & ~15;
        float sum = 0.f;
        for (int i = 0; i < 16; ++i) sum += EW[h0 + i];
        float aw = EW[t] / sum;
        SMW[0 * 128 + t] *= aw; SMW[1 * 128 + t] *= aw;
        SMW[2 * 128 + t] *= aw; SMW[3 * 128 + t] *= aw;
    }
    __syncthreads();

    {
        const int tok = t >> 7, sub = t & 127;
        const int h = sub >> 5, subsub = sub & 31, dseg = subsub & 15, half = subsub >> 4;
        const int smbase = (tok << 6) + (h << 4);
        const u16* Vb = VAL + (size_t)dseg * 8;
        float acc[8] = {0.f, 0.f, 0.f, 0.f, 0.f, 0.f, 0.f, 0.f};
        #pragma unroll
        for (int rr = 0; rr < 32; rr += 16) {
            u16x8 vreg[16];
            float wreg[16];
            #pragma unroll
            for (int q = 0; q < 16; ++q) {
                int pr = (half << 5) + rr + q;
                int s = pr >> 2, c = pr & 3;
                wreg[q] = SMW[c * 128 + smbase + s];
                vreg[q] = *(const u16x8*)(Vb + (size_t)SMI[c * 128 + smbase + s] * 128);
            }
            #pragma unroll
            for (int q = 0; q < 16; ++q)
                #pragma unroll
                for (int j = 0; j < 8; ++j) acc[j] += wreg[q] * bf2f(vreg[q][j]);
        }
        #pragma unroll
        for (int j = 0; j < 8; ++j) acc[j] += __shfl_xor(acc[j], 16, 64);
        if (!half) {
            u16x8 o;
            #pragma unroll
            for (int j = 0; j < 8; ++j) o[j] = f2bf(acc[j]);
            *(u16x8*)(S + (size_t)(tok0 + tok) * 512 + (h << 7) + (dseg << 3)) = o;
        }
    }
}

// ===========================================================================
// Standalone kernels (R7 fallback path)
// ===========================================================================
template<int ACT, int OUTM, int OUT_BF16, int BN>
__global__ __launch_bounds__(256) void gemm_kn(
    const u16* __restrict__ A, const u16* __restrict__ Bt,
    const u16* __restrict__ bias, void* __restrict__ Cv,
    int M, int K, int ldc, int nbase, const int* __restrict__ flag)
{
    __shared__ __align__(16) u16 smem[9216];
    int f32o = (OUTM == 2) ? *flag : 0;
    gemm_body<ACT, OUTM, OUT_BF16, BN>(smem, blockIdx.x, A, Bt, bias, Cv, M, K, ldc, nbase, f32o);
}

template<int CIN, int POS, int BN>
__global__ __launch_bounds__(256) void conv_gemm(
    const u16* __restrict__ A, const u16* __restrict__ X,
    const u16* __restrict__ bias, u16* __restrict__ Cv, int M)
{
    __shared__ __align__(16) u16 smem[9216];
    conv_body<CIN, POS, BN>(smem, blockIdx.x, A, X, bias, Cv, M);
}

__global__ __launch_bounds__(256) void val_conv1_k(
    const u16* __restrict__ AVW, const u16* __restrict__ CATT,
    const u16* __restrict__ vb, u16* __restrict__ VAL,
    const u16* __restrict__ AW1, const u16* __restrict__ X0,
    const u16* __restrict__ cb1, u16* __restrict__ CH1)
{
    __shared__ __align__(16) u16 smem[9216];
    int bid = blockIdx.x;
    if (bid < 960) gemm_body<0, 1, 1, 64>(smem, bid, AVW, CATT, vb, VAL, 128, 256, 0, 0, 0);
    else           conv_body<128, 0, 64>(smem, bid - 960, AW1, X0, cb1, CH1, 256);
}

__global__ __launch_bounds__(256) void prep_fused(MegaArgs g, int* __restrict__ FLAG)
{
    __shared__ __align__(16) u16 Ts[128 * 66];
    const int t = threadIdx.x;
    unsigned int w = ((const unsigned int*)g.f00)[t];
    float pa = fabsf(bf2f((u16)(w & 0xFFFFu)));
    int cnt = __syncthreads_count(pa > 1e-6f && pa < 1e4f);
    const int f32 = (cnt < 128);
    if (blockIdx.x == 0 && t == 0) *FLAG = f32;
    prep_unit(blockIdx.x, t, f32, g, Ts);
}

__global__ void msda_sample(const float* __restrict__ PA, const u16* __restrict__ VAL,
                            u16* __restrict__ S)
{
    __shared__ __align__(16) char smem[5120];
    // map 6144 blocks of 128 thr -> 3072 units of 2 tokens with 256-thr layout:
    // emulate by running unit with 128 threads handling ONE token (t>>7 == 0).
    // Simpler: run R7-style directly — one token per block.
    int*   SMI = (int*)smem;                           // [4][64]
    float* SMW = (float*)(smem + 1024);                // [4][64]
    float* LG  = (float*)(smem + 2048);                // [64]
    float* EW  = (float*)(smem + 2304);                // [64]
    int bid = blockIdx.x;                              // 6144 = 8 * 768
    int tok = ((bid & 7) * 768) + (bid >> 3);
    int t = threadIdx.x;                               // 128
    int b = tok / 1536, hw = tok % 1536;
    int hp = hw / 48, wp = hw % 48;

    if (t < 64) {
        int l = (t >> 3) & 1, p = t & 7, h = t >> 4;
        int orow = h * 32 + l * 16 + p * 2;
        float offx = PA[(size_t)orow * 6144 + tok];
        float offy = PA[(size_t)(orow + 1) * 6144 + tok];
        LG[t]      = PA[(size_t)(128 + h * 16 + l * 8 + p) * 6144 + tok];
        float Wl = l ? 48.f : 96.f, Hl = l ? 32.f : 64.f;
        int iWl = l ? 48 : 96, iHl = l ? 32 : 64;
        int base = l ? 6144 : 0;
        float locx = (wp + 0.5f) / 48.f + offx / Wl;
        float locy = (hp + 0.5f) / 32.f + offy / Hl;
        float x = locx * Wl - 0.5f;
        float y = locy * Hl - 0.5f;
        float xf = floorf(x), yf = floorf(y);
        float fx = x - xf, fy = y - yf;
        int ix = (int)xf, iy = (int)yf;
        int vrow = b * 7680 + base;
        float w00 = (1.f - fx) * (1.f - fy), w01 = fx * (1.f - fy);
        float w10 = (1.f - fx) * fy,         w11 = fx * fy;
        bool vx0 = (unsigned)ix < (unsigned)iWl,       vx1 = (unsigned)(ix + 1) < (unsigned)iWl;
        bool vy0 = (unsigned)iy < (unsigned)iHl,       vy1 = (unsigned)(iy + 1) < (unsigned)iHl;
        SMI[0 * 64 + t] = (vx0 && vy0) ? vrow + iy * iWl + ix           : 0;
        SMI[1 * 64 + t] = (vx1 && vy0) ? vrow + iy * iWl + ix + 1       : 0;
        SMI[2 * 64 + t] = (vx0 && vy1) ? vrow + (iy + 1) * iWl + ix     : 0;
        SMI[3 * 64 + t] = (vx1 && vy1) ? vrow + (iy + 1) * iWl + ix + 1 : 0;
        SMW[0 * 64 + t] = (vx0 && vy0) ? w00 : 0.f;
        SMW[1 * 64 + t] = (vx1 && vy0) ? w01 : 0.f;
        SMW[2 * 64 + t] = (vx0 && vy1) ? w10 : 0.f;
        SMW[3 * 64 + t] = (vx1 && vy1) ? w11 : 0.f;
    }
    __syncthreads();
    if (t < 64) {
        int h0 = t & ~15;
        float mx = -1e30f;
        for (int i = 0; i < 16; ++i) mx = fmaxf(mx, LG[h0 + i]);
        EW[t] = expf(LG[t] - mx);
    }
    __syncthreads();
    if (t < 64) {
        int h0 = t & ~15;
        float sum = 0.f;
        for (int i = 0; i < 16; ++i) sum += EW[h0 + i];
        float aw = EW[t] / sum;
        SMW[0 * 64 + t] *= aw; SMW[1 * 64 + t] *= aw;
        SMW[2 * 64 + t] *= aw; SMW[3 * 64 + t] *= aw;
    }
    __syncthreads();

    const int h = t >> 5, sub = t & 31, dseg = sub & 15, half = sub >> 4;
    const u16* Vb = VAL + (size_t)dseg * 8;
    float acc[8] = {0.f, 0.f, 0.f, 0.f, 0.f, 0.f, 0.f, 0.f};
    #pragma unroll
    for (int rr = 0; rr < 32; rr += 16) {
        u16x8 vreg[16];
        float wreg[16];
        #pragma unroll
        for (int q = 0; q < 16; ++q) {
            int pr = (half << 5) + rr + q;
            int s = pr >> 2, c = pr & 3;
            wreg[q] = SMW[c * 64 + (h << 4) + s];
            vreg[q] = *(const u16x8*)(Vb + (size_t)SMI[c * 64 + (h << 4) + s] * 128);
        }
        #pragma unroll
        for (int q = 0; q < 16; ++q)
            #pragma unroll
            for (int j = 0; j < 8; ++j) acc[j] += wreg[q] * bf2f(vreg[q][j]);
    }
    #pragma unroll
    for (int j = 0; j < 8; ++j) acc[j] += __shfl_xor(acc[j], 16, 64);
    if (!half) {
        u16x8 o;
        #pragma unroll
        for (int j = 0; j < 8; ++j) o[j] = f2bf(acc[j]);
        *(u16x8*)(S + (size_t)tok * 512 + (h << 7) + (dseg << 3)) = o;
    }
}

// ===========================================================================
// Cooperative mega-kernel: all phases grid-strided, grid.sync between.
// ===========================================================================
__global__ __launch_bounds__(256, 4) void mega(MegaArgs g)
{
    cg::grid_group grid = cg::this_grid();
    __shared__ __align__(16) char smem[18432];
    u16* sm16 = (u16*)smem;
    const int t = threadIdx.x;
    const int B = blockIdx.x, G = gridDim.x;

    unsigned int w = ((const unsigned int*)g.f00)[t];
    float pa = fabsf(bf2f((u16)(w & 0xFFFFu)));
    int cnt = __syncthreads_count(pa > 1e-6f && pa < 1e4f);
    const int f32 = (cnt < 128);

    u16* cb1 = g.SB;       u16* cb2 = g.SB + 256; u16* cb3 = g.SB + 384;
    u16* vb  = g.SB + 512; u16* ob0 = g.SB + 896; u16* ob1 = g.SB + 1024;

    for (int u = B; u < 4774; u += G) { __syncthreads(); prep_unit(u, t, f32, g, sm16); }
    grid.sync();
    for (int u = B; u < 1344; u += G) {
        if (u < 960) gemm_body<0, 1, 1, 64>(sm16, u, g.AVW, g.CATT, vb, g.VAL, 128, 256, 0, 0, 0);
        else         conv_body<128, 0, 64>(sm16, u - 960, g.AW1, g.X0, cb1, g.CH1, 256);
    }
    grid.sync();
    for (int u = B; u < 384; u += G) conv_body<256, 0, 32>(sm16, u, g.AW2, g.CH1, cb2, g.CH2, 128);
    grid.sync();
    for (int u = B; u < 384; u += G) conv_body<128, 1, 32>(sm16, u, g.AW3, g.CH2, cb3, g.QT0, 128);
    grid.sync();
    for (int u = B; u < 576; u += G) gemm_body<0, 0, 0, 32>(sm16, u, g.APJ0, g.QT0, g.BPJ0, g.PA, 192, 128, 6144, 0, 0);
    grid.sync();
    for (int u = B; u < 3072; u += G) { __syncthreads(); msda_unit(u, t, g.PA, g.VAL, g.S, smem); }
    grid.sync();
    for (int u = B; u < 384; u += G) gemm_body<0, 1, 1, 32>(sm16, u, g.AOP0, g.S, ob0, g.QT1, 128, 512, 0, 0, 0);
    grid.sync();
    for (int u = B; u < 576; u += G) gemm_body<0, 0, 0, 32>(sm16, u, g.APJ1, g.QT1, g.BPJ1, g.PA, 192, 128, 6144, 0, 0);
    grid.sync();
    for (int u = B; u < 3072; u += G) { __syncthreads(); msda_unit(u, t, g.PA, g.VAL, g.S, smem); }
    grid.sync();
    for (int u = B; u < 384; u += G) gemm_body<0, 2, 1, 32>(sm16, u, g.AOP1, g.S, ob1, g.OUT, 128, 512, 0, 0, f32);
}

// ---------------------------------------------------------------------------
extern "C" void kernel_launch(void* const* d_in, const int* in_sizes, int n_in,
                              void* d_out, int out_size, void* d_ws, size_t ws_size,
                              hipStream_t stream)
{
    (void)in_sizes; (void)n_in; (void)out_size; (void)ws_size;

    char* ws = (char*)d_ws;
    size_t off = 0;
    auto alloc = [&](size_t bytes) { size_t o = off; off += (bytes + 255) & ~(size_t)255; return o; };
    int*   FLAG = (int*)(ws + alloc(256));
    u16*   AW1  = (u16*)(ws + alloc(294912ull * 2));
    u16*   AW2  = (u16*)(ws + alloc(294912ull * 2));
    u16*   AW3  = (u16*)(ws + alloc(147456ull * 2));
    u16*   AVW  = (u16*)(ws + alloc(32768ull * 2));
    u16*   APJ0 = (u16*)(ws + alloc(24576ull * 2));
    u16*   APJ1 = (u16*)(ws + alloc(24576ull * 2));
    u16*   AOP0 = (u16*)(ws + alloc(65536ull * 2));
    u16*   AOP1 = (u16*)(ws + alloc(65536ull * 2));
    u16*   BPJ0 = (u16*)(ws + alloc(512));
    u16*   BPJ1 = (u16*)(ws + alloc(512));
    u16*   SB   = (u16*)(ws + alloc(1152ull * 2));
    u16*   VAL  = (u16*)(ws + alloc(30720ull * 128 * 2));
    u16*   X0   = (u16*)(ws + alloc(6144ull * 128 * 2));
    u16*   CH1  = (u16*)(ws + alloc(6144ull * 256 * 2));
    u16*   CH2  = (u16*)(ws + alloc(6144ull * 128 * 2));
    u16*   QT0  = (u16*)(ws + alloc(6144ull * 128 * 2));
    u16*   QT1  = (u16*)(ws + alloc(6144ull * 128 * 2));
    char*  R    = ws + alloc(30720ull * 256 * 2);          // union: CATT | PA+S
    u16*   CATT = (u16*)R;
    float* PA   = (float*)R;
    u16*   S    = (u16*)(R + 192ull * 6144 * 4);

    u16* cb1C = SB + 0;   u16* cb2C = SB + 256;  u16* cb3C = SB + 384;
    u16* vbC  = SB + 512;
    u16* ob0C = SB + 896; u16* ob1C = SB + 1024;

    MegaArgs ga;
    const int widx[21] = {4,5,6,7,8,9,10,11,12, 13,14,15,16,17,18, 19,20,21,22,23,24};
    for (int i = 0; i < 21; ++i) ga.a.p[i] = d_in[widx[i]];
    ga.f00 = d_in[0]; ga.f01 = d_in[1]; ga.f10 = d_in[2]; ga.f11 = d_in[3];
    ga.AW1 = AW1; ga.AW2 = AW2; ga.AW3 = AW3; ga.AVW = AVW;
    ga.APJ0 = APJ0; ga.APJ1 = APJ1; ga.AOP0 = AOP0; ga.AOP1 = AOP1;
    ga.BPJ0 = BPJ0; ga.BPJ1 = BPJ1; ga.SB = SB;
    ga.CATT = CATT; ga.X0 = X0; ga.VAL = VAL; ga.CH1 = CH1; ga.CH2 = CH2;
    ga.QT0 = QT0; ga.QT1 = QT1; ga.S = S; ga.PA = PA; ga.OUT = d_out;

    // ---- attempt cooperative mega-kernel with queried grid size ----
    bool coop_done = false;
    int nb = 0;
    hipError_t qe = hipOccupancyMaxActiveBlocksPerMultiprocessor(&nb, (const void*)mega, 256, 0);
    if (qe == hipSuccess && nb > 0) {
        int grid = nb * 256;                       // 256 CUs on MI355X
        if (grid > 1024) grid = 1024;
        void* kargs[] = { &ga };
        hipError_t le = hipLaunchCooperativeKernel((void*)mega, dim3(grid), dim3(256),
                                                   kargs, 0, stream);
        if (le == hipSuccess) coop_done = true;
        else (void)hipGetLastError();              // clear error state
    } else {
        (void)hipGetLastError();
    }
    if (coop_done) return;

    // ---- fallback: exact R7 multi-dispatch path ----
    prep_fused<<<4774, 256, 0, stream>>>(ga, FLAG);
    val_conv1_k<<<960 + 384, 256, 0, stream>>>(AVW, CATT, vbC, VAL, AW1, X0, cb1C, CH1);
    conv_gemm<256, 0, 32><<<2 * 192, 256, 0, stream>>>(AW2, CH1, cb2C, CH2, 128);
    conv_gemm<128, 1, 32><<<2 * 192, 256, 0, stream>>>(AW3, CH2, cb3C, QT0, 128);
    gemm_kn<0, 0, 0, 32><<<3 * 192, 256, 0, stream>>>(APJ0, QT0, BPJ0, PA, 192, 128, 6144, 0, FLAG);
    msda_sample<<<6144, 128, 0, stream>>>(PA, VAL, S);
    gemm_kn<0, 1, 1, 32><<<2 * 192, 256, 0, stream>>>(AOP0, S, ob0C, QT1, 128, 512, 0, 0, FLAG);
    gemm_kn<0, 0, 0, 32><<<3 * 192, 256, 0, stream>>>(APJ1, QT1, BPJ1, PA, 192, 128, 6144, 0, FLAG);
    msda_sample<<<6144, 128, 0, stream>>>(PA, VAL, S);
    gemm_kn<0, 2, 1, 32><<<2 * 192, 256, 0, stream>>>(AOP1, S, ob1C, d_out, 128, 512, 0, 0, FLAG);
}

// Round 13
// 142.049 us; speedup vs baseline: 5.2144x; 5.2144x over previous
//
#include <hip/hip_runtime.h>
#include <hip/hip_bf16.h>

typedef unsigned short u16;
typedef u16   u16x8 __attribute__((ext_vector_type(8)));
typedef short s16x8 __attribute__((ext_vector_type(8)));
typedef float f32x4 __attribute__((ext_vector_type(4)));

__device__ __forceinline__ float bf2f(u16 u) {
    union { unsigned int i; float f; } v; v.i = ((unsigned int)u) << 16; return v.f;
}
__device__ __forceinline__ u16 f2bf(float f) {
    unsigned int x = __float_as_uint(f);
    return (u16)((x + 0x7fffu + ((x >> 16) & 1u)) >> 16);   // RNE
}
__device__ __forceinline__ float ldv(const void* p, size_t i, int f32) {
    return f32 ? ((const float*)p)[i] : bf2f(((const u16*)p)[i]);
}

struct P21 { const void* p[21]; };
// p[]: 0 cw1,1 cb1,2 cw2,3 cb2,4 cw3,5 cb3,6 vw,7 vb,8 lvl,
//      9 sw0,10 sb0,11 aw0,12 ab0,13 ow0,14 ob0, 15 sw1,16 sb1,17 aw1,18 ab1,19 ow1,20 ob1

struct Args {
    P21 a;
    const void *f00, *f01, *f10, *f11;
    u16 *AW1, *AW2, *AW3, *AVW, *APJ0, *APJ1, *AOP1, *BPJ0, *BPJ1, *SB;
    u16 *OPW0, *ZB, *W1, *B1;
    u16 *CATT, *X0, *VAL, *CH1, *CH2, *QT0, *S;
    float* PA;
};

// ===========================================================================
// GEMM core, BK=64, tile 64 x BN (BN = 64 or 32). 4 waves.
// OUTM=0: C[m][nbase+n] (ldc). OUTM=1: C^T[nbase+n][m] bounce. OUTM=2: NCHW out.
// ===========================================================================
template<int ACT, int OUTM, int OUT_BF16, int BN>
__device__ __forceinline__ void gemm_body(
    u16* __restrict__ smem, int bid,
    const u16* __restrict__ A, const u16* __restrict__ Bt,
    const u16* __restrict__ bias, void* __restrict__ Cv,
    int M, int K, int ldc, int nbase, int f32o)
{
    constexpr int NF = BN >> 4;
    u16 (*As)[72] = (u16(*)[72])smem;
    u16 (*Bs)[72] = (u16(*)[72])(smem + 4608);

    const int t    = threadIdx.x;
    const int wv   = t >> 6, lane = t & 63;
    const int fr   = lane & 15, fg = lane >> 4;
    const int tiles_m = M >> 6;
    const int bm = bid % tiles_m, bn = bid / tiles_m;
    const int m0 = bm << 6, n0 = bn * BN;

    f32x4 acc[NF] = {};
    const int srow = t >> 2;
    const int scol = (t & 3) << 4;
    const int brow = (BN == 64) ? srow : (t >> 3);
    const int bcol = (BN == 64) ? scol : ((t & 7) << 3);
    const u16* Ap = A  + (size_t)(m0 + srow) * K + scol;
    const u16* Bp = Bt + (size_t)(n0 + brow) * K + bcol;

    const int ns = K >> 6;
    uint4 av0 = *(const uint4*)Ap, av1 = *(const uint4*)(Ap + 8);
    uint4 bv0 = *(const uint4*)Bp, bv1 = {0,0,0,0};
    if constexpr (BN == 64) bv1 = *(const uint4*)(Bp + 8);
    for (int s = 0; s < ns; ++s) {
        __syncthreads();
        *(uint4*)&As[srow][scol]     = av0;  *(uint4*)&As[srow][scol + 8] = av1;
        *(uint4*)&Bs[brow][bcol]     = bv0;
        if constexpr (BN == 64) *(uint4*)&Bs[brow][bcol + 8] = bv1;
        __syncthreads();
        if (s + 1 < ns) {
            const u16* An = Ap + ((s + 1) << 6);
            const u16* Bn = Bp + ((s + 1) << 6);
            av0 = *(const uint4*)An;  av1 = *(const uint4*)(An + 8);
            bv0 = *(const uint4*)Bn;
            if constexpr (BN == 64) bv1 = *(const uint4*)(Bn + 8);
        }
        union U { uint4 q; s16x8 v; };
        #pragma unroll
        for (int kk = 0; kk < 2; ++kk) {
            U af; af.q = *(const uint4*)&As[(wv << 4) + fr][(kk << 5) + (fg << 3)];
            U bf[NF];
            #pragma unroll
            for (int j = 0; j < NF; ++j)
                bf[j].q = *(const uint4*)&Bs[(j << 4) + fr][(kk << 5) + (fg << 3)];
            #pragma unroll
            for (int j = 0; j < NF; ++j)
                acc[j] = __builtin_amdgcn_mfma_f32_16x16x32_bf16(af.v, bf[j].v, acc[j], 0, 0, 0);
        }
    }

    float vv[NF][4];
    #pragma unroll
    for (int r = 0; r < 4; ++r) {
        float bvv = bf2f(bias[m0 + (wv << 4) + (fg << 2) + r]);
        #pragma unroll
        for (int j = 0; j < NF; ++j) {
            float v = acc[j][r] + bvv;
            if (ACT) v = (v >= 0.f) ? v : 0.1f * v;
            vv[j][r] = v;
        }
    }

    if constexpr (OUTM == 0) {
        #pragma unroll
        for (int j = 0; j < NF; ++j)
            #pragma unroll
            for (int r = 0; r < 4; ++r) {
                size_t idx = (size_t)(m0 + (wv << 4) + (fg << 2) + r) * ldc
                           + (nbase + n0 + (j << 4) + fr);
                if (OUT_BF16) ((u16*)Cv)[idx] = f2bf(vv[j][r]);
                else          ((float*)Cv)[idx] = vv[j][r];
            }
    } else if constexpr (OUTM == 1) {
        __syncthreads();
        u16* bb = smem;                                 // [BN n][72 m]
        #pragma unroll
        for (int j = 0; j < NF; ++j)
            #pragma unroll
            for (int r = 0; r < 4; ++r)
                bb[((j << 4) + fr) * 72 + (wv << 4) + (fg << 2) + r] = f2bf(vv[j][r]);
        __syncthreads();
        if constexpr (BN == 64) {
            int row = t >> 2, seg = (t & 3) << 4;
            const uint4* src = (const uint4*)&bb[row * 72 + seg];
            uint4* dst = (uint4*)((u16*)Cv + (size_t)(nbase + n0 + row) * M + m0 + seg);
            dst[0] = src[0];
            dst[1] = src[1];
        } else {
            int row = t >> 3, seg = (t & 7) << 3;
            const uint4* src = (const uint4*)&bb[row * 72 + seg];
            uint4* dst = (uint4*)((u16*)Cv + (size_t)(nbase + n0 + row) * M + m0 + seg);
            dst[0] = src[0];
        }
    } else {
        __syncthreads();
        constexpr int LDB = BN + 8;
        u16* bb = smem;                                 // [64 m][LDB n]
        #pragma unroll
        for (int j = 0; j < NF; ++j)
            #pragma unroll
            for (int r = 0; r < 4; ++r)
                bb[((wv << 4) + (fg << 2) + r) * LDB + (j << 4) + fr] = f2bf(vv[j][r]);
        __syncthreads();
        constexpr int EPT = BN / 4;
        int mrow = t >> 2, seg = (t & 3) * EPT;
        int b = n0 / 1536, hw0 = (n0 % 1536) + seg;
        size_t base = (size_t)(b * 128 + m0 + mrow) * 1536 + hw0;
        if (!f32o) {
            #pragma unroll
            for (int q = 0; q < EPT / 8; ++q)
                *(uint4*)((u16*)Cv + base + q * 8) = *(const uint4*)&bb[mrow * LDB + seg + q * 8];
        } else {
            float* dst = (float*)Cv + base;
            #pragma unroll
            for (int j = 0; j < EPT; ++j) dst[j] = bf2f(bb[mrow * LDB + seg + j]);
        }
    }
}

// ===========================================================================
// Implicit-GEMM 3x3 conv (pad 1), BK=64, tile 64 x BN. POS=1 fuses pos-enc.
// ===========================================================================
template<int CIN, int POS, int BN>
__device__ __forceinline__ void conv_body(
    u16* __restrict__ smem, int bid,
    const u16* __restrict__ A, const u16* __restrict__ X,
    const u16* __restrict__ bias, u16* __restrict__ Cv, int M)
{
    constexpr int NF = BN >> 4;
    u16 (*As)[72] = (u16(*)[72])smem;
    u16 (*Bs)[72] = (u16(*)[72])(smem + 4608);

    constexpr int NK2 = CIN / 64;
    constexpr int TOT = 9 * NK2;

    const int t    = threadIdx.x;
    const int wv   = t >> 6, lane = t & 63;
    const int fr   = lane & 15, fg = lane >> 4;
    const int tiles_m = M >> 6;
    const int bm = bid % tiles_m, bn = bid / tiles_m;
    const int m0 = bm << 6, n0 = bn * BN;

    const int srow = t >> 2;
    const int scol = (t & 3) << 4;
    const int brow = (BN == 64) ? srow : (t >> 3);
    const int bcol = (BN == 64) ? scol : ((t & 7) << 3);
    const int n  = n0 + brow;
    const int hw = n % 1536;
    const int hp = hw / 48, wp = hw % 48;
    const u16* Ar = A + (size_t)(m0 + srow) * (9 * CIN) + scol;

    f32x4 acc[NF] = {};

    auto ld = [&](int s, uint4& a0, uint4& a1, uint4& b0, uint4& b1) {
        int tap = s / NK2, k0 = (s % NK2) << 6;
        int dy = tap / 3 - 1, dx = tap % 3 - 1;
        bool vr = ((unsigned)(hp + dy) < 32u) && ((unsigned)(wp + dx) < 48u);
        const u16* Ap = Ar + tap * CIN + k0;
        a0 = *(const uint4*)Ap;  a1 = *(const uint4*)(Ap + 8);
        if (vr) {
            const u16* Bp = X + (size_t)(n + dy * 48 + dx) * CIN + bcol + k0;
            b0 = *(const uint4*)Bp;
            if constexpr (BN == 64) b1 = *(const uint4*)(Bp + 8);
        } else {
            b0 = uint4{0,0,0,0};  b1 = uint4{0,0,0,0};
        }
    };

    uint4 av0, av1, bv0, bv1;
    ld(0, av0, av1, bv0, bv1);
    for (int s = 0; s < TOT; ++s) {
        __syncthreads();
        *(uint4*)&As[srow][scol]     = av0;  *(uint4*)&As[srow][scol + 8] = av1;
        *(uint4*)&Bs[brow][bcol]     = bv0;
        if constexpr (BN == 64) *(uint4*)&Bs[brow][bcol + 8] = bv1;
        __syncthreads();
        if (s + 1 < TOT) ld(s + 1, av0, av1, bv0, bv1);
        union U { uint4 q; s16x8 v; };
        #pragma unroll
        for (int kk = 0; kk < 2; ++kk) {
            U af; af.q = *(const uint4*)&As[(wv << 4) + fr][(kk << 5) + (fg << 3)];
            U bf[NF];
            #pragma unroll
            for (int j = 0; j < NF; ++j)
                bf[j].q = *(const uint4*)&Bs[(j << 4) + fr][(kk << 5) + (fg << 3)];
            #pragma unroll
            for (int j = 0; j < NF; ++j)
                acc[j] = __builtin_amdgcn_mfma_f32_16x16x32_bf16(af.v, bf[j].v, acc[j], 0, 0, 0);
        }
    }

    float vv[NF][4];
    #pragma unroll
    for (int r = 0; r < 4; ++r) {
        float bvv = bf2f(bias[m0 + (wv << 4) + (fg << 2) + r]);
        #pragma unroll
        for (int j = 0; j < NF; ++j) {
            float v = acc[j][r] + bvv;
            vv[j][r] = (v >= 0.f) ? v : 0.1f * v;
        }
    }

    if (POS) {
        const float TWO_PI = 6.283185307179586f;
        #pragma unroll
        for (int j = 0; j < NF; ++j) {
            int ntok = n0 + (j << 4) + fr;
            int hw2 = ntok % 1536;
            int hp2 = hw2 / 48, wp2 = hw2 % 48;
            float yv = (float)(hp2 + 1) * (TWO_PI / (32.f + 1e-6f));
            float xv = (float)(wp2 + 1) * (TWO_PI / (48.f + 1e-6f));
            #pragma unroll
            for (int r = 0; r < 4; ++r) {
                int d = m0 + (wv << 4) + (fg << 2) + r;
                int mm = (d & 63) >> 1;
                float dim = exp2f((float)mm * (13.287712379549449f / 32.f));
                float val = ((d < 64) ? yv : xv) / dim;
                vv[j][r] += (d & 1) ? cosf(val) : sinf(val);
            }
        }
    }

    __syncthreads();
    u16* bb = smem;                                     // [BN n][72 m]
    #pragma unroll
    for (int j = 0; j < NF; ++j)
        #pragma unroll
        for (int r = 0; r < 4; ++r)
            bb[((j << 4) + fr) * 72 + (wv << 4) + (fg << 2) + r] = f2bf(vv[j][r]);
    __syncthreads();
    if constexpr (BN == 64) {
        int row = t >> 2, seg = (t & 3) << 4;
        const uint4* src = (const uint4*)&bb[row * 72 + seg];
        uint4* dst = (uint4*)(Cv + (size_t)(n0 + row) * M + m0 + seg);
        dst[0] = src[0];
        dst[1] = src[1];
    } else {
        int row = t >> 3, seg = (t & 7) << 3;
        const uint4* src = (const uint4*)&bb[row * 72 + seg];
        uint4* dst = (uint4*)(Cv + (size_t)(n0 + row) * M + m0 + seg);
        dst[0] = src[0];
    }
}

// ---------------------------------------------------------------------------
template<int ACT, int OUTM, int OUT_BF16, int BN>
__global__ __launch_bounds__(256) void gemm_kn(
    const u16* __restrict__ A, const u16* __restrict__ Bt,
    const u16* __restrict__ bias, void* __restrict__ Cv,
    int M, int K, int ldc, int nbase, const int* __restrict__ flag)
{
    __shared__ __align__(16) u16 smem[9216];
    int f32o = (OUTM == 2) ? *flag : 0;
    gemm_body<ACT, OUTM, OUT_BF16, BN>(smem, blockIdx.x, A, Bt, bias, Cv, M, K, ldc, nbase, f32o);
}

template<int CIN, int POS, int BN>
__global__ __launch_bounds__(256) void conv_gemm(
    const u16* __restrict__ A, const u16* __restrict__ X,
    const u16* __restrict__ bias, u16* __restrict__ Cv, int M)
{
    __shared__ __align__(16) u16 smem[9216];
    conv_body<CIN, POS, BN>(smem, blockIdx.x, A, X, bias, Cv, M);
}

// ===========================================================================
// fat kernel: value GEMM (960) || conv1 (384) || W1 = APJ1*op_w0^T (48)
// || b1 = APJ1*ob0 + BPJ1 (1 block)          — all depend only on prep.
// ===========================================================================
__global__ __launch_bounds__(256) void val_conv1_k(Args g)
{
    __shared__ __align__(16) u16 smem[9216];
    int bid = blockIdx.x;
    u16* cb1 = g.SB;
    u16* vb  = g.SB + 512;
    u16* ob0 = g.SB + 896;
    if (bid < 960) {
        gemm_body<0, 1, 1, 64>(smem, bid, g.AVW, g.CATT, vb, g.VAL, 128, 256, 0, 0, 0);
    } else if (bid < 1344) {
        conv_body<128, 0, 64>(smem, bid - 960, g.AW1, g.X0, cb1, g.CH1, 256);
    } else if (bid < 1392) {
        // W1[192][512] = APJ1[192][128] x OPW0[512][128]^T   (pure product)
        gemm_body<0, 0, 1, 32>(smem, bid - 1344, g.APJ1, g.OPW0, g.ZB, g.W1, 192, 128, 512, 0, 0);
    } else {
        // b1[m] = sum_k APJ1[m][k]*ob0[k] + BPJ1[m]
        int m = threadIdx.x;
        if (m < 192) {
            float s = bf2f(g.BPJ1[m]);
            const u16* row = g.APJ1 + (size_t)m * 128;
            for (int k = 0; k < 128; ++k) s += bf2f(row[k]) * bf2f(ob0[k]);
            g.B1[m] = f2bf(s);
        }
    }
}

// ===========================================================================
// fused prep: inline dtype detect, then one of
//   [0,3975)     : weight canon/transpose + OPW0 + ZB (1017536 elems)
//   [3975,4935)  : feature transpose -> CATT
//   [4935,5031)  : feature transpose -> X0
// ===========================================================================
__global__ __launch_bounds__(256) void prep_fused(Args g, int* __restrict__ FLAG)
{
    __shared__ __align__(16) u16 Ts[128 * 66];
    const int t = threadIdx.x;
    const P21& a = g.a;
    unsigned int w = ((const unsigned int*)g.f00)[t];
    float pa = fabsf(bf2f((u16)(w & 0xFFFFu)));
    int cnt = __syncthreads_count(pa > 1e-6f && pa < 1e4f);
    const int f32 = (cnt < 128);
    const int bid = blockIdx.x;
    if (bid == 0 && t == 0) *FLAG = f32;

    if (bid < 3975) {
        int gg = bid * 256 + t;
        if (gg < 294912) { int m = gg / 1152, rem = gg % 1152, tap = rem >> 7, ci = rem & 127;
            g.AW1[gg] = f2bf(ldv(a.p[0], (size_t)m * 1152 + ci * 9 + tap, f32)); return; }
        gg -= 294912;
        if (gg < 294912) { int m = gg / 2304, rem = gg % 2304, tap = rem >> 8, ci = rem & 255;
            g.AW2[gg] = f2bf(ldv(a.p[2], (size_t)m * 2304 + ci * 9 + tap, f32)); return; }
        gg -= 294912;
        if (gg < 147456) { int m = gg / 1152, rem = gg % 1152, tap = rem >> 7, ci = rem & 127;
            g.AW3[gg] = f2bf(ldv(a.p[4], (size_t)m * 1152 + ci * 9 + tap, f32)); return; }
        gg -= 147456;
        if (gg < 32768) { g.AVW[gg] = f2bf(ldv(a.p[6], gg, f32)); return; }
        gg -= 32768;
        if (gg < 24576) { int o = gg >> 7, d = gg & 127;
            g.APJ0[gg] = f2bf(o < 128 ? ldv(a.p[9], d * 128 + o, f32)
                                      : ldv(a.p[11], d * 64 + (o - 128), f32)); return; }
        gg -= 24576;
        if (gg < 24576) { int o = gg >> 7, d = gg & 127;
            g.APJ1[gg] = f2bf(o < 128 ? ldv(a.p[15], d * 128 + o, f32)
                                      : ldv(a.p[17], d * 64 + (o - 128), f32)); return; }
        gg -= 24576;
        if (gg < 65536) { int o = gg >> 9, k = gg & 511; g.AOP1[gg] = f2bf(ldv(a.p[19], k * 128 + o, f32)); return; }
        gg -= 65536;
        if (gg < 192) { g.BPJ0[gg] = f2bf(gg < 128 ? ldv(a.p[10], gg, f32) : ldv(a.p[12], gg - 128, f32)); return; }
        gg -= 192;
        if (gg < 192) { g.BPJ1[gg] = f2bf(gg < 128 ? ldv(a.p[16], gg, f32) : ldv(a.p[18], gg - 128, f32)); return; }
        gg -= 192;
        if (gg < 1152) {
            const int off[8] = {0, 256, 384, 512, 640, 896, 1024, 1152};
            const int src[7] = {1, 3, 5, 7, 8, 14, 20};
            int s = 0;
            #pragma unroll
            for (int i = 1; i < 7; ++i) s += (gg >= off[i]);
            g.SB[gg] = f2bf(ldv(a.p[src[s]], gg - off[s], f32)); return;
        }
        gg -= 1152;
        if (gg < 65536) { g.OPW0[gg] = f2bf(ldv(a.p[13], gg, f32)); return; }   // raw op_w0 [512][128]
        gg -= 65536;
        if (gg < 192) { g.ZB[gg] = 0; return; }
        return;
    }

    // feature transposes via LDS tile [128][66]
    const void* src; u16* dst;
    int b, hw0, HW, rowlen, coloff, lvl, addemb;
    if (bid < 4935) {
        int gg = bid - 3975;
        int half = gg & 1;  gg >>= 1;                 // 480 = 4b x 120 tiles
        b = gg / 120;  int tile = gg % 120;
        lvl = (tile >= 96) ? 1 : 0;
        int tl = lvl ? tile - 96 : tile;
        hw0 = tl << 6;
        HW = lvl ? 1536 : 6144;
        src = (half == 0) ? (lvl ? g.f01 : g.f00) : (lvl ? g.f11 : g.f10);
        dst = g.CATT + (size_t)(b * 7680 + lvl * 6144 + hw0) * 256;
        rowlen = 256; coloff = half << 7; addemb = 1;
    } else {
        int gg = bid - 4935;                          // 96 = 4b x 24 tiles
        b = gg / 24;  hw0 = (gg % 24) << 6;
        HW = 1536; src = g.f01;
        dst = g.X0 + (size_t)(b * 1536 + hw0) * 128;
        rowlen = 128; coloff = 0; lvl = 1; addemb = 0;
    }

    {
        int c = t >> 1, hseg = (t & 1) << 5;
        size_t base = (size_t)(b * 128 + c) * HW + hw0 + hseg;
        u16* dstl = &Ts[c * 66 + hseg];
        if (!f32) {
            const u16* s8 = (const u16*)src + base;
            *(uint4*)(dstl)      = *(const uint4*)(s8);
            *(uint4*)(dstl + 8)  = *(const uint4*)(s8 + 8);
            *(uint4*)(dstl + 16) = *(const uint4*)(s8 + 16);
            *(uint4*)(dstl + 24) = *(const uint4*)(s8 + 24);
        } else {
            const float* sf = (const float*)src + base;
            #pragma unroll
            for (int q = 0; q < 32; ++q) dstl[q] = f2bf(sf[q]);
        }
    }
    __syncthreads();
    {
        int tok = t & 63, cseg = (t >> 6) << 5;
        u16 outv[32];
        #pragma unroll
        for (int j = 0; j < 32; ++j) {
            float x = bf2f(Ts[(cseg + j) * 66 + tok]);
            if (addemb) x += ldv(a.p[8], lvl * 128 + cseg + j, f32);
            outv[j] = f2bf(x);
        }
        u16* drow = dst + (size_t)tok * rowlen + coloff + cseg;
        #pragma unroll
        for (int q = 0; q < 4; ++q)
            *(uint4*)(drow + q * 8) = *(const uint4*)(&outv[q * 8]);
    }
}

// ===========================================================================
// MSDeformAttn sampling (+softmax), batched gather (16 in flight), XCD swizzle
// ===========================================================================
__global__ void msda_sample(const float* __restrict__ PA, const u16* __restrict__ VAL,
                            u16* __restrict__ S)
{
    __shared__ int   SMI[4][64];
    __shared__ float SMW[4][64];
    __shared__ float LG[64];
    __shared__ float EW[64];
    int bid = blockIdx.x;                              // 6144 = 8 * 768
    int tok = ((bid & 7) * 768) + (bid >> 3);
    int t = threadIdx.x;                               // 128
    int b = tok / 1536, hw = tok % 1536;
    int hp = hw / 48, wp = hw % 48;

    if (t < 64) {
        int l = (t >> 3) & 1, p = t & 7, h = t >> 4;
        int orow = h * 32 + l * 16 + p * 2;
        float offx = PA[(size_t)orow * 6144 + tok];
        float offy = PA[(size_t)(orow + 1) * 6144 + tok];
        LG[t]      = PA[(size_t)(128 + h * 16 + l * 8 + p) * 6144 + tok];
        float Wl = l ? 48.f : 96.f, Hl = l ? 32.f : 64.f;
        int iWl = l ? 48 : 96, iHl = l ? 32 : 64;
        int base = l ? 6144 : 0;
        float locx = (wp + 0.5f) / 48.f + offx / Wl;
        float locy = (hp + 0.5f) / 32.f + offy / Hl;
        float x = locx * Wl - 0.5f;
        float y = locy * Hl - 0.5f;
        float xf = floorf(x), yf = floorf(y);
        float fx = x - xf, fy = y - yf;
        int ix = (int)xf, iy = (int)yf;
        int vrow = b * 7680 + base;
        float w00 = (1.f - fx) * (1.f - fy), w01 = fx * (1.f - fy);
        float w10 = (1.f - fx) * fy,         w11 = fx * fy;
        bool vx0 = (unsigned)ix < (unsigned)iWl,       vx1 = (unsigned)(ix + 1) < (unsigned)iWl;
        bool vy0 = (unsigned)iy < (unsigned)iHl,       vy1 = (unsigned)(iy + 1) < (unsigned)iHl;
        SMI[0][t] = (vx0 && vy0) ? vrow + iy * iWl + ix           : 0;
        SMI[1][t] = (vx1 && vy0) ? vrow + iy * iWl + ix + 1       : 0;
        SMI[2][t] = (vx0 && vy1) ? vrow + (iy + 1) * iWl + ix     : 0;
        SMI[3][t] = (vx1 && vy1) ? vrow + (iy + 1) * iWl + ix + 1 : 0;
        SMW[0][t] = (vx0 && vy0) ? w00 : 0.f;
        SMW[1][t] = (vx1 && vy0) ? w01 : 0.f;
        SMW[2][t] = (vx0 && vy1) ? w10 : 0.f;
        SMW[3][t] = (vx1 && vy1) ? w11 : 0.f;
    }
    __syncthreads();
    if (t < 64) {
        int h0 = t & ~15;
        float mx = -1e30f;
        for (int i = 0; i < 16; ++i) mx = fmaxf(mx, LG[h0 + i]);
        EW[t] = expf(LG[t] - mx);
    }
    __syncthreads();
    if (t < 64) {
        int h0 = t & ~15;
        float sum = 0.f;
        for (int i = 0; i < 16; ++i) sum += EW[h0 + i];
        float aw = EW[t] / sum;
        SMW[0][t] *= aw; SMW[1][t] *= aw;
        SMW[2][t] *= aw; SMW[3][t] *= aw;
    }
    __syncthreads();

    const int h = t >> 5, sub = t & 31, dseg = sub & 15, half = sub >> 4;
    const u16* Vb = VAL + (size_t)dseg * 8;
    float acc[8] = {0.f, 0.f, 0.f, 0.f, 0.f, 0.f, 0.f, 0.f};
    #pragma unroll
    for (int rr = 0; rr < 32; rr += 16) {
        u16x8 vreg[16];
        float wreg[16];
        #pragma unroll
        for (int q = 0; q < 16; ++q) {
            int pr = (half << 5) + rr + q;
            int s = pr >> 2, c = pr & 3;
            wreg[q] = SMW[c][(h << 4) + s];
            vreg[q] = *(const u16x8*)(Vb + (size_t)SMI[c][(h << 4) + s] * 128);
        }
        #pragma unroll
        for (int q = 0; q < 16; ++q)
            #pragma unroll
            for (int j = 0; j < 8; ++j) acc[j] += wreg[q] * bf2f(vreg[q][j]);
    }
    #pragma unroll
    for (int j = 0; j < 8; ++j) acc[j] += __shfl_xor(acc[j], 16, 64);
    if (!half) {
        u16x8 o;
        #pragma unroll
        for (int j = 0; j < 8; ++j) o[j] = f2bf(acc[j]);
        *(u16x8*)(S + (size_t)tok * 512 + (h << 7) + (dseg << 3)) = o;
    }
}

// ---------------------------------------------------------------------------
extern "C" void kernel_launch(void* const* d_in, const int* in_sizes, int n_in,
                              void* d_out, int out_size, void* d_ws, size_t ws_size,
                              hipStream_t stream)
{
    (void)in_sizes; (void)n_in; (void)out_size; (void)ws_size;

    char* ws = (char*)d_ws;
    size_t off = 0;
    auto alloc = [&](size_t bytes) { size_t o = off; off += (bytes + 255) & ~(size_t)255; return o; };
    int*   FLAG = (int*)(ws + alloc(256));
    u16*   AW1  = (u16*)(ws + alloc(294912ull * 2));
    u16*   AW2  = (u16*)(ws + alloc(294912ull * 2));
    u16*   AW3  = (u16*)(ws + alloc(147456ull * 2));
    u16*   AVW  = (u16*)(ws + alloc(32768ull * 2));
    u16*   APJ0 = (u16*)(ws + alloc(24576ull * 2));
    u16*   APJ1 = (u16*)(ws + alloc(24576ull * 2));
    u16*   AOP1 = (u16*)(ws + alloc(65536ull * 2));
    u16*   BPJ0 = (u16*)(ws + alloc(512));
    u16*   BPJ1 = (u16*)(ws + alloc(512));
    u16*   SB   = (u16*)(ws + alloc(1152ull * 2));
    u16*   OPW0 = (u16*)(ws + alloc(65536ull * 2));
    u16*   ZB   = (u16*)(ws + alloc(512));
    u16*   W1   = (u16*)(ws + alloc(98304ull * 2));
    u16*   B1   = (u16*)(ws + alloc(512));
    u16*   VAL  = (u16*)(ws + alloc(30720ull * 128 * 2));
    u16*   X0   = (u16*)(ws + alloc(6144ull * 128 * 2));
    u16*   CH1  = (u16*)(ws + alloc(6144ull * 256 * 2));
    u16*   CH2  = (u16*)(ws + alloc(6144ull * 128 * 2));
    u16*   QT0  = (u16*)(ws + alloc(6144ull * 128 * 2));
    char*  R    = ws + alloc(30720ull * 256 * 2);          // union: CATT | PA+S
    u16*   CATT = (u16*)R;
    float* PA   = (float*)R;
    u16*   S    = (u16*)(R + 192ull * 6144 * 4);

    u16* cb2C = SB + 256;  u16* cb3C = SB + 384;
    u16* ob1C = SB + 1024;

    Args g;
    const int widx[21] = {4,5,6,7,8,9,10,11,12, 13,14,15,16,17,18, 19,20,21,22,23,24};
    for (int i = 0; i < 21; ++i) g.a.p[i] = d_in[widx[i]];
    g.f00 = d_in[0]; g.f01 = d_in[1]; g.f10 = d_in[2]; g.f11 = d_in[3];
    g.AW1 = AW1; g.AW2 = AW2; g.AW3 = AW3; g.AVW = AVW;
    g.APJ0 = APJ0; g.APJ1 = APJ1; g.AOP1 = AOP1;
    g.BPJ0 = BPJ0; g.BPJ1 = BPJ1; g.SB = SB;
    g.OPW0 = OPW0; g.ZB = ZB; g.W1 = W1; g.B1 = B1;
    g.CATT = CATT; g.X0 = X0; g.VAL = VAL; g.CH1 = CH1; g.CH2 = CH2;
    g.QT0 = QT0; g.S = S; g.PA = PA;

    // 1. fused prep: weights + OPW0/ZB + CATT + X0 (+FLAG)
    prep_fused<<<5031, 256, 0, stream>>>(g, FLAG);

    // 2. value GEMM || conv1 || W1 fuse || b1 fuse
    val_conv1_k<<<1393, 256, 0, stream>>>(g);

    // 3. conv2, conv3(+pos)
    conv_gemm<256, 0, 32><<<2 * 192, 256, 0, stream>>>(AW2, CH1, cb2C, CH2, 128);
    conv_gemm<128, 1, 32><<<2 * 192, 256, 0, stream>>>(AW3, CH2, cb3C, QT0, 128);

    // 4. attention block 0: proj0 -> msda0
    gemm_kn<0, 0, 0, 32><<<3 * 192, 256, 0, stream>>>(APJ0, QT0, BPJ0, PA, 192, 128, 6144, 0, FLAG);
    msda_sample<<<6144, 128, 0, stream>>>(PA, VAL, S);

    // 5. fused out0∘proj1: PA1 = W1*S0 + b1 -> msda1
    gemm_kn<0, 0, 0, 32><<<3 * 192, 256, 0, stream>>>(W1, S, B1, PA, 192, 512, 6144, 0, FLAG);
    msda_sample<<<6144, 128, 0, stream>>>(PA, VAL, S);

    // 6. out1 -> NCHW d_out
    gemm_kn<0, 2, 1, 32><<<2 * 192, 256, 0, stream>>>(AOP1, S, ob1C, d_out, 128, 512, 0, 0, FLAG);
}